// Round 6
// baseline (525.283 us; speedup 1.0000x reference)
//
#include <hip/hip_runtime.h>
#include <hip/hip_fp16.h>

// GCN link-prediction forward. CSR aggregation with XCD-sliced, slice-major
// gather tables (per-XCD L2-resident); fp16 storage; fp16 MFMA GEMMs.
// Inputs: x[N,256] f32, train_edges[2,E] i32, pos[2,E] i32, neg[2,E] i32,
//         W1[256,256], b1[256], W2[256,128], b2[128]  (all f32)
// Output: logits[2E] f32.

#define NFEAT 256
#define HID   256
#define OUTF  128
#define SCAN_T 1024

typedef _Float16 f16x8 __attribute__((ext_vector_type(8)));
typedef float    f32x4 __attribute__((ext_vector_type(4)));

// ---------------- degree ----------------
__global__ void k_init_deg(float* __restrict__ deg, int n) {
    int i = blockIdx.x * blockDim.x + threadIdx.x;
    if (i < n) deg[i] = 1.0f;   // self-loop
}

__global__ void k_count_deg(const int* __restrict__ ei, float* __restrict__ deg, int E) {
    int e = blockIdx.x * blockDim.x + threadIdx.x;
    if (e < E) atomicAdd(&deg[ei[E + e]], 1.0f);   // dst row
}

// ---------------- scan: rowptr/cursor from deg, dinv in place ----------------
__global__ __launch_bounds__(SCAN_T) void k_scan(
        float* __restrict__ deg_dinv, int* __restrict__ rowptr,
        int* __restrict__ cursor, int n) {
    __shared__ int swsum[16];
    __shared__ int s_total;
    __shared__ int s_chunk;
    const int t    = threadIdx.x;
    const int wave = t >> 6;
    const int lane = t & 63;
    if (t == 0) s_total = 0;

    for (int base = 0; base < n; base += SCAN_T) {
        int i = base + t;
        float dg = 1.0f;
        int v = 0;
        if (i < n) { dg = deg_dinv[i]; v = (int)dg - 1; }  // edge count (no self)
        int sc = v;
#pragma unroll
        for (int off = 1; off < 64; off <<= 1) {
            int y = __shfl_up(sc, off);
            if (lane >= off) sc += y;
        }
        if (lane == 63) swsum[wave] = sc;
        __syncthreads();
        if (t < 16) {
            int w = swsum[t];
            int scw = w;
#pragma unroll
            for (int off = 1; off < 16; off <<= 1) {
                int y = __shfl_up(scw, off);
                if (t >= off) scw += y;
            }
            swsum[t] = scw - w;
            if (t == 15) s_chunk = scw;
        }
        __syncthreads();
        int rp = s_total + swsum[wave] + (sc - v);
        if (i < n) {
            rowptr[i] = rp;
            cursor[i] = rp;
            deg_dinv[i] = rsqrtf(dg);
        }
        __syncthreads();
        if (t == 0) s_total += s_chunk;
        __syncthreads();
    }
    if (t == 0) rowptr[n] = s_total;
}

// ---------------- fill CSR adjacency (src ids grouped by dst) ----------------
__global__ void k_fill(const int* __restrict__ ei, int* __restrict__ cursor,
                       int* __restrict__ eidx, int E) {
    int e = blockIdx.x * blockDim.x + threadIdx.x;
    if (e < E) {
        int s = ei[e];
        int d = ei[E + e];
        int p = atomicAdd(&cursor[d], 1);
        eidx[p] = s;
    }
}

// ---------------- W transpose+convert: Wt[m][k] = (half)W[k][m] ----------------
__global__ __launch_bounds__(256) void k_wt(const float* __restrict__ W,
                                            __half* __restrict__ Wt, int K, int M) {
    __shared__ float tile[32][33];
    int k0 = blockIdx.x * 32, m0 = blockIdx.y * 32;
    int tx = threadIdx.x & 31, ty = threadIdx.x >> 5;  // ty 0..7
#pragma unroll
    for (int r = 0; r < 4; ++r)
        tile[ty + r * 8][tx] = W[(size_t)(k0 + ty + r * 8) * M + m0 + tx];
    __syncthreads();
#pragma unroll
    for (int r = 0; r < 4; ++r)
        Wt[(size_t)(m0 + ty + r * 8) * K + k0 + tx] = __float2half(tile[tx][ty + r * 8]);
}

// ---------------- MFMA GEMM: out = (half)(dinv[r] * A @ Wt^T) ----------------
// Block: 256 threads = 4 waves (2x2). Block tile (2*MT*16) x 128, wave (MT*16) x 64.
// A: [n][K] (f32 if AF32 else f16). Wt: [M][K] f16. K % 32 == 0.
// Output is SLICE-MAJOR: out[(col>>SWL)][row][col & (SW-1)], SW = 1<<SWL feats/slice.
template <int MT, bool AF32, int SWL>
__global__ __launch_bounds__(256) void k_gemm_mfma(
        const void* __restrict__ Aptr, const __half* __restrict__ Wt,
        const float* __restrict__ dinv, __half* __restrict__ outp,
        int n, int K, int M) {
    constexpr int BM = 2 * MT * 16;
    __shared__ __half As[BM][40];      // [row][k], +8 pad: 2-way banks (free)
    __shared__ __half Bs[128][40];     // [col][k]
    __shared__ __half Cs[4][16][72];   // per-wave C repack (16B-aligned rows)

    const int t    = threadIdx.x;
    const int wave = t >> 6;
    const int lane = t & 63;
    const int row0 = blockIdx.x * BM;
    const int col0 = blockIdx.y * 128;
    const int wm = wave >> 1, wn = wave & 1;
    const int lr = lane & 15;          // fragment m/n index
    const int kq = lane >> 4;          // k-quad: k = kq*8 + j

    f32x4 acc[MT][4];
#pragma unroll
    for (int i = 0; i < MT; ++i)
#pragma unroll
        for (int j = 0; j < 4; ++j) acc[i][j] = (f32x4){0.f, 0.f, 0.f, 0.f};

    for (int k0 = 0; k0 < K; k0 += 32) {
        // ---- stage A tile: BM rows x 32 k ----
        if (AF32) {
            const float* A = (const float*)Aptr;
#pragma unroll
            for (int it = 0; it < BM * 8 / 256; ++it) {
                int q = t + it * 256;
                int r = q >> 3, c4 = q & 7;       // c4: which 4-float chunk
                int gr = min(row0 + r, n - 1);
                float4 v = *(const float4*)&A[(size_t)gr * K + k0 + c4 * 4];
                __half2* dst = (__half2*)&As[r][c4 * 4];
                dst[0] = __floats2half2_rn(v.x, v.y);
                dst[1] = __floats2half2_rn(v.z, v.w);
            }
        } else {
            const __half* A = (const __half*)Aptr;
#pragma unroll
            for (int it = 0; it < BM * 4 / 256; ++it) {
                int q = t + it * 256;
                int r = q >> 2, c8 = q & 3;       // c8: which 8-half chunk
                int gr = min(row0 + r, n - 1);
                *(float4*)&As[r][c8 * 8] = *(const float4*)&A[(size_t)gr * K + k0 + c8 * 8];
            }
        }
        // ---- stage B tile: 128 cols x 32 k from Wt ----
#pragma unroll
        for (int it = 0; it < 2; ++it) {
            int q = t + it * 256;
            int r = q >> 2, c8 = q & 3;
            *(float4*)&Bs[r][c8 * 8] = *(const float4*)&Wt[(size_t)(col0 + r) * K + k0 + c8 * 8];
        }
        __syncthreads();

        f16x8 b[4];
#pragma unroll
        for (int j = 0; j < 4; ++j)
            b[j] = *(const f16x8*)&Bs[wn * 64 + j * 16 + lr][kq * 8];
#pragma unroll
        for (int i = 0; i < MT; ++i) {
            f16x8 a = *(const f16x8*)&As[wm * MT * 16 + i * 16 + lr][kq * 8];
#pragma unroll
            for (int j = 0; j < 4; ++j)
                acc[i][j] = __builtin_amdgcn_mfma_f32_16x16x32_f16(a, b[j], acc[i][j], 0, 0, 0);
        }
        __syncthreads();
    }

    // ---- epilogue: scale by dinv, f16 convert, repack via LDS, slice-major stores ----
    constexpr int SW = 1 << SWL;
#pragma unroll
    for (int i = 0; i < MT; ++i) {
        int gr0 = row0 + wm * MT * 16 + i * 16;
        float dv[4];
#pragma unroll
        for (int r = 0; r < 4; ++r)
            dv[r] = dinv[min(gr0 + kq * 4 + r, n - 1)];
        __syncthreads();   // protect Cs reuse across i iterations
#pragma unroll
        for (int j = 0; j < 4; ++j)
#pragma unroll
            for (int r = 0; r < 4; ++r)
                Cs[wave][kq * 4 + r][j * 16 + lr] = __float2half(acc[i][j][r] * dv[r]);
        __syncthreads();
        int r1 = lane >> 3, c1 = (lane & 7) * 8;
#pragma unroll
        for (int h = 0; h < 2; ++h) {
            int grow = gr0 + r1 + h * 8;
            if (grow < n) {
                int col = col0 + wn * 64 + c1;    // multiple of 8; 8 halves stay in-slice
                size_t oidx = ((size_t)(col >> SWL) * n + grow) * SW + (col & (SW - 1));
                *(float4*)&outp[oidx] = *(const float4*)&Cs[wave][r1 + h * 8][c1];
            }
        }
    }
}

// ---------------- layer-1 aggregate (XCD-sliced): 8 slices x 32 feats ----------------
// g1s slice-major [8][n][32]; h1 row-major fp16. 16 lanes per node; slice = bx % 8.
__global__ void k_agg1(const int* __restrict__ rowptr, const int* __restrict__ eidx,
                       const __half* __restrict__ g1s, const float* __restrict__ dinv,
                       const float* __restrict__ bias, __half* __restrict__ out, int n) {
    const int slice = blockIdx.x & 7;
    const int node  = (blockIdx.x >> 3) * 16 + (threadIdx.x >> 4);
    const int sl    = threadIdx.x & 15;
    if (node >= n) return;
    int j   = rowptr[node];
    int end = rowptr[node + 1];
    float sc = dinv[node];
    const __half* base = g1s + (size_t)slice * n * 32 + sl * 2;

    float2 acc = __half22float2(*(const __half2*)&base[(size_t)node * 32]);  // self
    for (; j + 1 < end; j += 2) {
        int s0 = eidx[j];
        int s1 = eidx[j + 1];
        float2 v0 = __half22float2(*(const __half2*)&base[(size_t)s0 * 32]);
        float2 v1 = __half22float2(*(const __half2*)&base[(size_t)s1 * 32]);
        acc.x += v0.x + v1.x; acc.y += v0.y + v1.y;
    }
    if (j < end) {
        int s0 = eidx[j];
        float2 v0 = __half22float2(*(const __half2*)&base[(size_t)s0 * 32]);
        acc.x += v0.x; acc.y += v0.y;
    }
    int f = slice * 32 + sl * 2;
    float2 b = *(const float2*)&bias[f];
    __half2 r = __floats2half2_rn(fmaxf(sc * acc.x + b.x, 0.f),
                                  fmaxf(sc * acc.y + b.y, 0.f));
    *(__half2*)&out[(size_t)node * HID + f] = r;
}

// ---------------- layer-2 aggregate (XCD-sliced): 8 slices x 16 feats ----------------
// g2s slice-major [8][n][16]; z row-major fp16. 8 lanes per node; slice = bx % 8.
__global__ void k_agg2(const int* __restrict__ rowptr, const int* __restrict__ eidx,
                       const __half* __restrict__ g2s, const float* __restrict__ dinv,
                       const float* __restrict__ bias, __half* __restrict__ out, int n) {
    const int slice = blockIdx.x & 7;
    const int node  = (blockIdx.x >> 3) * 32 + (threadIdx.x >> 3);
    const int sl    = threadIdx.x & 7;
    if (node >= n) return;
    int j   = rowptr[node];
    int end = rowptr[node + 1];
    float sc = dinv[node];
    const __half* base = g2s + (size_t)slice * n * 16 + sl * 2;

    float2 acc = __half22float2(*(const __half2*)&base[(size_t)node * 16]);  // self
    for (; j + 1 < end; j += 2) {
        int s0 = eidx[j];
        int s1 = eidx[j + 1];
        float2 v0 = __half22float2(*(const __half2*)&base[(size_t)s0 * 16]);
        float2 v1 = __half22float2(*(const __half2*)&base[(size_t)s1 * 16]);
        acc.x += v0.x + v1.x; acc.y += v0.y + v1.y;
    }
    if (j < end) {
        int s0 = eidx[j];
        float2 v0 = __half22float2(*(const __half2*)&base[(size_t)s0 * 16]);
        acc.x += v0.x; acc.y += v0.y;
    }
    int f = slice * 16 + sl * 2;
    float2 b = *(const float2*)&bias[f];
    __half2 r = __floats2half2_rn(sc * acc.x + b.x, sc * acc.y + b.y);
    *(__half2*)&out[(size_t)node * OUTF + f] = r;
}

// ---------------- decode: logits[e] = dot(z[a], z[b]) over 128 dims (fp16 z) -----
__global__ void k_decode(const int* __restrict__ pos, const int* __restrict__ neg,
                         const __half* __restrict__ z, float* __restrict__ out, int E) {
    size_t gid = (size_t)blockIdx.x * blockDim.x + threadIdx.x;
    int e  = (int)(gid >> 4);
    int sl = (int)(threadIdx.x & 15);
    if (e >= 2 * E) return;
    int a, b;
    if (e < E) { a = pos[e];     b = pos[E + e]; }
    else       { a = neg[e - E]; b = neg[e];     }
    union HF4 { float4 f; __half2 h[4]; };
    HF4 ua, ub;
    ua.f = ((const float4*)(z + (size_t)a * OUTF))[sl];
    ub.f = ((const float4*)(z + (size_t)b * OUTF))[sl];
    float p = 0.f;
#pragma unroll
    for (int k = 0; k < 4; ++k) {
        float2 fa = __half22float2(ua.h[k]);
        float2 fb = __half22float2(ub.h[k]);
        p += fa.x * fb.x + fa.y * fb.y;
    }
    p += __shfl_xor(p, 1);
    p += __shfl_xor(p, 2);
    p += __shfl_xor(p, 4);
    p += __shfl_xor(p, 8);
    if (sl == 0) out[e] = p;
}

extern "C" void kernel_launch(void* const* d_in, const int* in_sizes, int n_in,
                              void* d_out, int out_size, void* d_ws, size_t ws_size,
                              hipStream_t stream) {
    const float* x   = (const float*)d_in[0];
    const int*   tei = (const int*)d_in[1];
    const int*   pos = (const int*)d_in[2];
    const int*   neg = (const int*)d_in[3];
    const float* W1  = (const float*)d_in[4];
    const float* b1  = (const float*)d_in[5];
    const float* W2  = (const float*)d_in[6];
    const float* b2  = (const float*)d_in[7];
    float* out = (float*)d_out;

    const int N = in_sizes[0] / NFEAT;    // 50000
    const int E = in_sizes[1] / 2;        // 800000

    char* ws = (char*)d_ws;
    size_t off = 0;
    __half* g1s = (__half*)(ws + off);                 // slice-major [8][N][32]
    __half* g2s = (__half*)(ws + off);                 // slice-major [8][N][16] (g1 dead)
    __half* zh  = (__half*)(ws + off + (size_t)N * OUTF * 2);   // row-major [N][128]
    off += (size_t)N * HID * 2;
    __half* h1h = (__half*)(ws + off);  off += (size_t)N * HID * 2;  // row-major [N][256]
    float*  dinv = (float*)(ws + off);  off += (size_t)N * 4;
    int* rowptr = (int*)(ws + off);     off += (size_t)(N + 1) * 4;
    int* cursor = (int*)(ws + off);     off += (size_t)N * 4;
    int* eidx   = (int*)(ws + off);     off += (size_t)E * 4;
    __half* W1t = (__half*)(ws + off);  off += (size_t)NFEAT * HID * 2;
    __half* W2t = (__half*)(ws + off);  off += (size_t)HID * OUTF * 2;

    // 0) weight transpose+convert
    { dim3 g(NFEAT / 32, HID / 32);  k_wt<<<g, 256, 0, stream>>>(W1, W1t, NFEAT, HID); }
    { dim3 g(HID / 32, OUTF / 32);   k_wt<<<g, 256, 0, stream>>>(W2, W2t, HID, OUTF); }

    // 1) degree -> scan -> CSR fill (shared by both layers)
    k_init_deg<<<(N + 255) / 256, 256, 0, stream>>>(dinv, N);
    k_count_deg<<<(E + 255) / 256, 256, 0, stream>>>(tei, dinv, E);
    k_scan<<<1, SCAN_T, 0, stream>>>(dinv, rowptr, cursor, N);
    k_fill<<<(E + 255) / 256, 256, 0, stream>>>(tei, cursor, eidx, E);

    // 2) layer 1: g1s = (half, slice-major) dinv*(x@W1); h1 = relu(dinv*(agg+self)+b1)
    {
        dim3 grid((N + 127) / 128, HID / 128);
        k_gemm_mfma<4, true, 5><<<grid, 256, 0, stream>>>(x, W1t, dinv, g1s, N, NFEAT, HID);
        int nblk = 8 * ((N + 15) / 16);
        k_agg1<<<nblk, 256, 0, stream>>>(rowptr, eidx, g1s, dinv, b1, h1h, N);
    }

    // 3) layer 2: g2s = (half, slice-major) dinv*(h1@W2); z = dinv*(agg+self)+b2
    {
        dim3 grid((N + 63) / 64, OUTF / 128);
        k_gemm_mfma<2, false, 4><<<grid, 256, 0, stream>>>(h1h, W2t, dinv, g2s, N, HID, OUTF);
        int nblk = 8 * ((N + 31) / 32);
        k_agg2<<<nblk, 256, 0, stream>>>(rowptr, eidx, g2s, dinv, b2, zh, N);
    }

    // 4) decode
    {
        size_t nth = (size_t)2 * E * 16;   // 16 lanes per edge
        k_decode<<<(int)((nth + 255) / 256), 256, 0, stream>>>(pos, neg, zh, out, E);
    }
}